// Round 2
// baseline (2280.192 us; speedup 1.0000x reference)
//
#include <hip/hip_runtime.h>
#include <hip/hip_bf16.h>
#include <math.h>

#define NN 50000
#define EE 800000
#define IN_D 256
#define HH 128
#define OUT_D 64
#define DEPTH 3

// ---------------- generic GEMM with fused epilogues ----------------
// out[n,m] = epi( sum_k A(n,k)*B[k*M+m] + bias[m] ),  A(n,k)= k<K1 ? A1[n*K1+k] : A2[n*(K-K1)+k-K1]
// One block = 32 rows x full M (M<=128): safe for in-place mu update (block reads only its own rows).
enum { EPI_NONE=0, EPI_TANH=1, EPI_SIG=2, EPI_CUPD=3, EPI_MUUPD=4, EPI_RELU=5 };

template<int EPI>
__global__ __launch_bounds__(256) void gemm_k(
    const float* __restrict__ A1, const float* __restrict__ A2, int K1, int K,
    const float* __restrict__ B, const float* __restrict__ bias,
    float* __restrict__ Out, float* __restrict__ Cbuf,
    const float* __restrict__ Ibuf, const float* __restrict__ Tbuf,
    int Nrows, int M)
{
    __shared__ float As[32][33];
    __shared__ float Bs[32][132];
    const int rb  = blockIdx.x * 32;
    const int tid = threadIdx.x;
    const int tx  = tid & 31;   // col base tx*4 (covers 128)
    const int ty  = tid >> 5;   // row base ty*4 (covers 32)
    float acc[4][4] = {};
    for (int k0 = 0; k0 < K; k0 += 32) {
        for (int i = tid; i < 32*32; i += 256) {
            int r = i >> 5, cc = i & 31;
            int gr = rb + r, gk = k0 + cc;
            float v = 0.f;
            if (gr < Nrows) {
                if (gk < K1) v = A1[(size_t)gr*K1 + gk];
                else         v = A2[(size_t)gr*(K-K1) + (gk-K1)];
            }
            As[r][cc] = v;
        }
        for (int i = tid; i < 32*128; i += 256) {
            int r = i >> 7, cc = i & 127;
            Bs[r][cc] = (cc < M) ? B[(size_t)(k0+r)*M + cc] : 0.f;
        }
        __syncthreads();
        #pragma unroll
        for (int k = 0; k < 32; ++k) {
            float a[4], b[4];
            #pragma unroll
            for (int i=0;i<4;i++) a[i] = As[ty*4+i][k];
            #pragma unroll
            for (int j=0;j<4;j++) b[j] = Bs[k][tx*4+j];
            #pragma unroll
            for (int i=0;i<4;i++)
                #pragma unroll
                for (int j=0;j<4;j++)
                    acc[i][j] = fmaf(a[i], b[j], acc[i][j]);
        }
        __syncthreads();
    }
    #pragma unroll
    for (int i=0;i<4;i++) {
        int gr = rb + ty*4 + i;
        if (gr >= Nrows) continue;
        #pragma unroll
        for (int j=0;j<4;j++) {
            int gc = tx*4 + j;
            if (gc >= M) continue;
            float v = acc[i][j];
            if (bias) v += bias[gc];
            size_t o = (size_t)gr*M + gc;
            if (EPI==EPI_NONE)  Out[o] = v;
            if (EPI==EPI_TANH)  Out[o] = tanhf(v);
            if (EPI==EPI_SIG)   Out[o] = 1.f/(1.f+expf(-v));
            if (EPI==EPI_CUPD)  { float fg = 1.f/(1.f+expf(-v)); Cbuf[o] = fg*Cbuf[o] + Ibuf[o]*Tbuf[o]; }
            if (EPI==EPI_MUUPD) { float og = 1.f/(1.f+expf(-v)); Out[o] = og * tanhf(Cbuf[o]); }
            if (EPI==EPI_RELU)  Out[o] = fmaxf(v, 0.f);
        }
    }
}

// ---------------- GAT pieces ----------------
__global__ __launch_bounds__(64) void eler_k(const float* __restrict__ z,
    const float* __restrict__ al, const float* __restrict__ ar,
    float* __restrict__ el, float* __restrict__ er)
{
    int n = blockIdx.x, l = threadIdx.x;
    float z0 = z[(size_t)n*HH + l], z1 = z[(size_t)n*HH + l + 64];
    float pl = z0*al[l] + z1*al[l+64];
    float pr = z0*ar[l] + z1*ar[l+64];
    #pragma unroll
    for (int off=32; off; off>>=1){ pl += __shfl_down(pl,off); pr += __shfl_down(pr,off); }
    if (l==0){ el[n]=pl; er[n]=pr; }
}

__global__ void edge_k(const int* __restrict__ src, const int* __restrict__ dst,
                       const float* __restrict__ el, const float* __restrict__ er,
                       float* __restrict__ ev)
{
    int e = blockIdx.x*256 + threadIdx.x;
    if (e >= EE) return;
    float v = el[src[e]] + er[dst[e]];
    ev[e] = v >= 0.f ? v : 0.2f*v;
}

// one wave per dst node: softmax over incoming edges + weighted gather of z[src]
__global__ __launch_bounds__(64) void agg_k(const float* __restrict__ z,
    const float* __restrict__ ev, const int* __restrict__ eidx,
    const int* __restrict__ rp, const int* __restrict__ deg,
    const int* __restrict__ src, const float* __restrict__ bias,
    float* __restrict__ hout)
{
    int n = blockIdx.x, l = threadIdx.x;
    int start = rp[n], cnt = deg[n];
    float m = -1e30f;
    for (int i=l; i<cnt; i+=64) m = fmaxf(m, ev[eidx[start+i]]);
    #pragma unroll
    for (int off=1; off<64; off<<=1) m = fmaxf(m, __shfl_xor(m, off));
    float s = 0.f;
    for (int i=l; i<cnt; i+=64) s += expf(ev[eidx[start+i]] - m);
    #pragma unroll
    for (int off=1; off<64; off<<=1) s += __shfl_xor(s, off);
    float inv = 1.f / fmaxf(s, 1e-16f);
    float a0 = 0.f, a1 = 0.f;
    for (int i=0; i<cnt; ++i) {
        int e = eidx[start+i];
        int sn = src[e];
        float w = expf(ev[e]-m) * inv;
        a0 = fmaf(w, z[(size_t)sn*HH + l],      a0);
        a1 = fmaf(w, z[(size_t)sn*HH + l + 64], a1);
    }
    hout[(size_t)n*HH + l]      = tanhf(a0 + bias[l]);
    hout[(size_t)n*HH + l + 64] = tanhf(a1 + bias[l+64]);
}

// ---------------- CSR build (by dst) ----------------
__global__ void count_k(const int* __restrict__ dst, int* __restrict__ deg){
    int e = blockIdx.x*256 + threadIdx.x;
    if (e < EE) atomicAdd(&deg[dst[e]], 1);
}
__global__ __launch_bounds__(256) void scan1_k(const int* __restrict__ deg, int* __restrict__ rp,
                                               int* __restrict__ bsum, int n){
    __shared__ int s[256];
    int t = threadIdx.x, idx = blockIdx.x*256 + t;
    int v = (idx < n) ? deg[idx] : 0;
    s[t] = v; __syncthreads();
    for (int off=1; off<256; off<<=1){ int x = (t>=off)? s[t-off] : 0; __syncthreads(); s[t] += x; __syncthreads(); }
    if (idx < n) rp[idx] = s[t] - v;
    if (t == 255) bsum[blockIdx.x] = s[255];
}
__global__ __launch_bounds__(256) void scan2_k(int* __restrict__ bsum, int nb){
    __shared__ int s[256];
    int t = threadIdx.x;
    int v = (t < nb) ? bsum[t] : 0;
    s[t] = v; __syncthreads();
    for (int off=1; off<256; off<<=1){ int x = (t>=off)? s[t-off] : 0; __syncthreads(); s[t] += x; __syncthreads(); }
    if (t < nb) bsum[t] = s[t] - v;
}
__global__ void scan3_k(int* __restrict__ rp, const int* __restrict__ bsum, int n){
    int idx = blockIdx.x*256 + threadIdx.x;
    if (idx < n) rp[idx] += bsum[blockIdx.x];
}
__global__ void fill_k(const int* __restrict__ dst, const int* __restrict__ rp,
                       int* __restrict__ cursor, int* __restrict__ eidx){
    int e = blockIdx.x*256 + threadIdx.x;
    if (e >= EE) return;
    int d = dst[e];
    int pos = rp[d] + atomicAdd(&cursor[d], 1);
    eidx[pos] = e;
}

extern "C" void kernel_launch(void* const* d_in, const int* in_sizes, int n_in,
                              void* d_out, int out_size, void* d_ws, size_t ws_size,
                              hipStream_t stream)
{
    const float* x    = (const float*)d_in[0];
    const int*   src  = (const int*)d_in[1];
    const int*   dst  = (const int*)d_in[2];
    const float* wxW  = (const float*)d_in[3];
    const float* wxb  = (const float*)d_in[4];
    const float* gatW = (const float*)d_in[5];
    const float* gatb = (const float*)d_in[6];
    const float* attl = (const float*)d_in[7];
    const float* attr = (const float*)d_in[8];
    const float* igW  = (const float*)d_in[9];
    const float* igb  = (const float*)d_in[10];
    const float* fgW  = (const float*)d_in[11];
    const float* fgb  = (const float*)d_in[12];
    const float* ogW  = (const float*)d_in[13];
    const float* ogb  = (const float*)d_in[14];
    const float* stW  = (const float*)d_in[15];
    const float* stb  = (const float*)d_in[16];
    const float* outW = (const float*)d_in[17];
    const float* outb = (const float*)d_in[18];

    char* w = (char*)d_ws;
    auto alloc = [&](size_t bytes)->char* { char* p = w; w += (bytes + 255) & ~(size_t)255; return p; };
    const size_t NH = (size_t)NN * HH;
    float* h0mu   = (float*)alloc(NH*4);          // h0, then mu
    float* cbuf   = (float*)alloc(NH*4);
    float* coll0  = (float*)alloc(NH*4);
    float* coll1  = (float*)alloc(NH*4);
    float* coll2  = (float*)alloc(NH*4);
    float* zT     = (float*)alloc(NH*4);          // z in GAT phase, tanh(st) in depth phase
    float* Ibuf   = (float*)alloc(NH*4);
    float* el     = (float*)alloc((size_t)NN*4);
    float* er     = (float*)alloc((size_t)NN*4);
    float* ev     = (float*)alloc((size_t)EE*4);
    int*   deg    = (int*)alloc((size_t)NN*4);
    int*   cursor = (int*)alloc((size_t)NN*4);
    int*   rp     = (int*)alloc((size_t)NN*4);
    int*   bsum   = (int*)alloc(256*4);
    int*   eidx   = (int*)alloc((size_t)EE*4);
    float* coll[3] = {coll0, coll1, coll2};

    // ---- CSR by dst (rebuilt every call; src/dst are constant inputs) ----
    hipMemsetAsync(deg, 0, (size_t)NN*4, stream);
    hipMemsetAsync(cursor, 0, (size_t)NN*4, stream);
    count_k<<<(EE+255)/256, 256, 0, stream>>>(dst, deg);
    int nb = (NN+255)/256;
    scan1_k<<<nb, 256, 0, stream>>>(deg, rp, bsum, NN);
    scan2_k<<<1, 256, 0, stream>>>(bsum, nb);
    scan3_k<<<nb, 256, 0, stream>>>(rp, bsum, NN);
    fill_k<<<(EE+255)/256, 256, 0, stream>>>(dst, rp, cursor, eidx);

    const int gN = (NN + 31) / 32;

    // ---- h0 = x @ wxW + wxb ----
    gemm_k<EPI_NONE><<<gN, 256, 0, stream>>>(
        x, (const float*)nullptr, IN_D, IN_D, wxW, wxb, h0mu, nullptr, nullptr, nullptr, NN, HH);

    // ---- GAT layers ----
    const float* hin = h0mu;
    for (int i = 0; i < DEPTH; ++i) {
        gemm_k<EPI_NONE><<<gN, 256, 0, stream>>>(
            hin, (const float*)nullptr, HH, HH, gatW + (size_t)i*HH*HH, nullptr,
            zT, nullptr, nullptr, nullptr, NN, HH);
        eler_k<<<NN, 64, 0, stream>>>(zT, attl + i*HH, attr + i*HH, el, er);
        edge_k<<<(EE+255)/256, 256, 0, stream>>>(src, dst, el, er, ev);
        agg_k<<<NN, 64, 0, stream>>>(zT, ev, eidx, rp, deg, src, gatb + i*HH, coll[i]);
        hin = coll[i];
    }

    // ---- depth (LSTM-style) ----
    hipMemsetAsync(cbuf, 0, NH*4, stream);
    for (int i = 0; i < DEPTH; ++i) {
        const float* A1 = coll[i];
        const float* A2 = h0mu;  // mu
        size_t wo = (size_t)i * 2*HH*HH;
        gemm_k<EPI_TANH><<<gN, 256, 0, stream>>>(
            A1, A2, HH, 2*HH, stW + wo, stb + i*HH, zT, nullptr, nullptr, nullptr, NN, HH);
        gemm_k<EPI_SIG><<<gN, 256, 0, stream>>>(
            A1, A2, HH, 2*HH, igW + wo, igb + i*HH, Ibuf, nullptr, nullptr, nullptr, NN, HH);
        gemm_k<EPI_CUPD><<<gN, 256, 0, stream>>>(
            A1, A2, HH, 2*HH, fgW + wo, fgb + i*HH, nullptr, cbuf, Ibuf, zT, NN, HH);
        gemm_k<EPI_MUUPD><<<gN, 256, 0, stream>>>(
            A1, A2, HH, 2*HH, ogW + wo, ogb + i*HH, h0mu, cbuf, nullptr, nullptr, NN, HH);
    }

    // ---- out = relu(mu @ outW + outb) -> f32 ----
    gemm_k<EPI_RELU><<<gN, 256, 0, stream>>>(
        h0mu, (const float*)nullptr, HH, HH, outW, outb, (float*)d_out, nullptr, nullptr, nullptr, NN, OUT_D);
}

// Round 3
// 740.345 us; speedup vs baseline: 3.0799x; 3.0799x over previous
//
#include <hip/hip_runtime.h>
#include <math.h>
#include <type_traits>

#define NN 50000
#define EE 800000
#define IN_D 256
#define HH 128
#define OUT_D 64
#define DEPTH 3

typedef unsigned short u16;
typedef __bf16  bf16x8 __attribute__((ext_vector_type(8)));
typedef short   short8 __attribute__((ext_vector_type(8)));
typedef float   f32x4  __attribute__((ext_vector_type(4)));

__device__ __forceinline__ u16 f2b(float f){
    unsigned u = __float_as_uint(f);
    u += 0x7fff + ((u>>16)&1);            // round-to-nearest-even
    return (u16)(u>>16);
}
__device__ __forceinline__ float b2f(u16 h){ return __uint_as_float(((unsigned)h)<<16); }

// ---------------- MFMA GEMM with fused epilogues ----------------
// out[n,m] = epi( sum_k A(n,k)*B[k][m] + bias[m] ),  A(n,k) = k<K1 ? A1 : A2 (concat)
// Bt is B transposed: [M][K] bf16.  Block = 64 rows x M cols, 4 waves (2x2).
// In-place safety (MUUPD): a block stages only its own 64 rows, writes after its k-loop.
enum { EPI_BF=0, EPI_TANH, EPI_SIG, EPI_CUPD, EPI_MUUPD, EPI_RELU };

template<int EPI, int MT, typename TA>   // MT = n-tiles per wave; M = MT*32
__global__ __launch_bounds__(256) void mgemm_k(
    const TA* __restrict__ A1, const TA* __restrict__ A2, int K1, int K,
    const u16* __restrict__ Bt, const float* __restrict__ bias,
    void* __restrict__ Out, float* __restrict__ Cbuf,
    const float* __restrict__ Ibuf, const float* __restrict__ Tbuf,
    int Nrows)
{
    constexpr int M = MT*32;
    __shared__ u16 As[64*40];     // [64 rows][32 k] padded to 40 (80B stride: 2-way bank = free)
    __shared__ u16 Bs[128*40];    // [M rows of Bt][32 k] padded
    const int tid  = threadIdx.x;
    const int lane = tid & 63;
    const int w    = tid >> 6;
    const int wrow = (w>>1)*32, wcol = (w&1)*(MT*16);
    const int rb   = blockIdx.x*64;
    f32x4 acc[2][MT] = {};
    const int arow = tid>>2, aseg = tid&3;
    const int gr = rb + arow;
    const int ml = lane & 15, kh = (lane>>4)*8;

    for (int k0 = 0; k0 < K; k0 += 32) {
        const void* Ap; int rs, kk;
        if (k0 < K1) { Ap = A1; rs = K1;    kk = k0; }
        else         { Ap = A2; rs = K-K1;  kk = k0-K1; }
        short8 v = {};
        if (gr < Nrows) {
            if constexpr (std::is_same<TA,float>::value) {
                const float* p = (const float*)Ap + (size_t)gr*rs + kk + aseg*8;
                float4 x0 = *(const float4*)p;
                float4 x1 = *(const float4*)(p+4);
                v[0]=(short)f2b(x0.x); v[1]=(short)f2b(x0.y); v[2]=(short)f2b(x0.z); v[3]=(short)f2b(x0.w);
                v[4]=(short)f2b(x1.x); v[5]=(short)f2b(x1.y); v[6]=(short)f2b(x1.z); v[7]=(short)f2b(x1.w);
            } else {
                v = *(const short8*)((const u16*)Ap + (size_t)gr*rs + kk + aseg*8);
            }
        }
        *(short8*)&As[arow*40 + aseg*8] = v;
        #pragma unroll
        for (int c = 0; c < MT/2; ++c) {
            int idx = tid + c*256;
            int n = idx>>2, sg = idx&3;
            *(short8*)&Bs[n*40 + sg*8] = *(const short8*)(Bt + (size_t)n*K + k0 + sg*8);
        }
        __syncthreads();
        bf16x8 a0 = *(const bf16x8*)&As[(wrow      + ml)*40 + kh];
        bf16x8 a1 = *(const bf16x8*)&As[(wrow + 16 + ml)*40 + kh];
        #pragma unroll
        for (int j = 0; j < MT; ++j) {
            bf16x8 bf = *(const bf16x8*)&Bs[(wcol + j*16 + ml)*40 + kh];
            acc[0][j] = __builtin_amdgcn_mfma_f32_16x16x32_bf16(a0, bf, acc[0][j], 0,0,0);
            acc[1][j] = __builtin_amdgcn_mfma_f32_16x16x32_bf16(a1, bf, acc[1][j], 0,0,0);
        }
        __syncthreads();
    }
    const int rq = (lane>>4)*4;
    #pragma unroll
    for (int i = 0; i < 2; ++i) {
        #pragma unroll
        for (int r = 0; r < 4; ++r) {
            int row = rb + wrow + i*16 + rq + r;
            if (row >= Nrows) continue;
            #pragma unroll
            for (int j = 0; j < MT; ++j) {
                int gc = wcol + j*16 + ml;
                float vv = acc[i][j][r];
                if (bias) vv += bias[gc];
                size_t o = (size_t)row*M + gc;
                if (EPI==EPI_BF)    ((u16*)Out)[o] = f2b(vv);
                if (EPI==EPI_TANH)  ((float*)Out)[o] = tanhf(vv);
                if (EPI==EPI_SIG)   ((float*)Out)[o] = 1.f/(1.f+expf(-vv));
                if (EPI==EPI_CUPD)  { float fg = 1.f/(1.f+expf(-vv)); Cbuf[o] = fg*Cbuf[o] + Ibuf[o]*Tbuf[o]; }
                if (EPI==EPI_MUUPD) { float og = 1.f/(1.f+expf(-vv)); ((u16*)Out)[o] = f2b(og * tanhf(Cbuf[o])); }
                if (EPI==EPI_RELU)  ((float*)Out)[o] = fmaxf(vv, 0.f);
            }
        }
    }
}

// ---------------- weight transpose+convert: dst[m*K+k] = src[k*M+m] ----------------
struct WT  { const float* s; u16* d; int K; int M; };
struct WTs { WT t[17]; };
__global__ __launch_bounds__(256) void wtrans_k(WTs ws){
    const WT t = ws.t[blockIdx.y];
    int o = blockIdx.x*256 + threadIdx.x;
    int tot = t.K * t.M;
    if (o >= tot) return;
    int m = o / t.K, k = o - m*t.K;
    t.d[o] = f2b(t.s[(size_t)k*t.M + m]);
}

// ---------------- GAT pieces ----------------
__global__ __launch_bounds__(64) void eler_k(const u16* __restrict__ z,
    const float* __restrict__ al, const float* __restrict__ ar,
    float* __restrict__ el, float* __restrict__ er)
{
    int n = blockIdx.x, l = threadIdx.x;
    float z0 = b2f(z[(size_t)n*HH + l]), z1 = b2f(z[(size_t)n*HH + l + 64]);
    float pl = z0*al[l] + z1*al[l+64];
    float pr = z0*ar[l] + z1*ar[l+64];
    #pragma unroll
    for (int off=32; off; off>>=1){ pl += __shfl_down(pl,off); pr += __shfl_down(pr,off); }
    if (l==0){ el[n]=pl; er[n]=pr; }
}

__global__ void edge_k(const int* __restrict__ src, const int* __restrict__ dst,
                       const float* __restrict__ el, const float* __restrict__ er,
                       float* __restrict__ ev)
{
    int e = blockIdx.x*256 + threadIdx.x;
    if (e >= EE) return;
    float v = el[src[e]] + er[dst[e]];
    ev[e] = v >= 0.f ? v : 0.2f*v;
}

// one wave per dst node: softmax over incoming edges + weighted gather of z[src]
// gather phase: 4 edge-slots x 16 lanes x 8 channels (one 16B load/lane/edge)
__global__ __launch_bounds__(64) void agg_k(const u16* __restrict__ z,
    const float* __restrict__ ev, const int* __restrict__ eidx,
    const int* __restrict__ rp, const int* __restrict__ deg,
    const int* __restrict__ src, const float* __restrict__ bias,
    u16* __restrict__ hout)
{
    int n = blockIdx.x, lane = threadIdx.x;
    int start = rp[n], cnt = deg[n];
    float m = -1e30f;
    for (int i=lane; i<cnt; i+=64) m = fmaxf(m, ev[eidx[start+i]]);
    #pragma unroll
    for (int off=1; off<64; off<<=1) m = fmaxf(m, __shfl_xor(m, off));
    float s = 0.f;
    for (int i=lane; i<cnt; i+=64) s += expf(ev[eidx[start+i]] - m);
    #pragma unroll
    for (int off=1; off<64; off<<=1) s += __shfl_xor(s, off);
    float inv = 1.f / fmaxf(s, 1e-16f);

    const int slot = lane >> 4;          // 0..3 edge slot
    const int ch   = (lane & 15) * 8;    // 8 channels per lane
    float acc[8] = {};
    for (int i = slot; i < cnt; i += 4) {
        int e = eidx[start+i];
        float wgt = expf(ev[e]-m) * inv;
        short8 v = *(const short8*)(z + (size_t)src[e]*HH + ch);
        #pragma unroll
        for (int j=0;j<8;j++) acc[j] = fmaf(wgt, b2f((u16)v[j]), acc[j]);
    }
    #pragma unroll
    for (int j=0;j<8;j++){ acc[j] += __shfl_xor(acc[j],16); acc[j] += __shfl_xor(acc[j],32); }
    if (slot == 0) {
        short8 o8;
        #pragma unroll
        for (int j=0;j<8;j++) o8[j] = (short)f2b(tanhf(acc[j] + bias[ch+j]));
        *(short8*)(hout + (size_t)n*HH + ch) = o8;
    }
}

// ---------------- CSR build (by dst) ----------------
__global__ void count_k(const int* __restrict__ dst, int* __restrict__ deg){
    int e = blockIdx.x*256 + threadIdx.x;
    if (e < EE) atomicAdd(&deg[dst[e]], 1);
}
__global__ __launch_bounds__(256) void scan1_k(const int* __restrict__ deg, int* __restrict__ rp,
                                               int* __restrict__ bsum, int n){
    __shared__ int s[256];
    int t = threadIdx.x, idx = blockIdx.x*256 + t;
    int v = (idx < n) ? deg[idx] : 0;
    s[t] = v; __syncthreads();
    for (int off=1; off<256; off<<=1){ int x = (t>=off)? s[t-off] : 0; __syncthreads(); s[t] += x; __syncthreads(); }
    if (idx < n) rp[idx] = s[t] - v;
    if (t == 255) bsum[blockIdx.x] = s[255];
}
__global__ __launch_bounds__(256) void scan2_k(int* __restrict__ bsum, int nb){
    __shared__ int s[256];
    int t = threadIdx.x;
    int v = (t < nb) ? bsum[t] : 0;
    s[t] = v; __syncthreads();
    for (int off=1; off<256; off<<=1){ int x = (t>=off)? s[t-off] : 0; __syncthreads(); s[t] += x; __syncthreads(); }
    if (t < nb) bsum[t] = s[t] - v;
}
__global__ void scan3_k(int* __restrict__ rp, const int* __restrict__ bsum, int n){
    int idx = blockIdx.x*256 + threadIdx.x;
    if (idx < n) rp[idx] += bsum[blockIdx.x];
}
__global__ void fill_k(const int* __restrict__ dst, const int* __restrict__ rp,
                       int* __restrict__ cursor, int* __restrict__ eidx){
    int e = blockIdx.x*256 + threadIdx.x;
    if (e >= EE) return;
    int d = dst[e];
    int pos = rp[d] + atomicAdd(&cursor[d], 1);
    eidx[pos] = e;
}

extern "C" void kernel_launch(void* const* d_in, const int* in_sizes, int n_in,
                              void* d_out, int out_size, void* d_ws, size_t ws_size,
                              hipStream_t stream)
{
    const float* x    = (const float*)d_in[0];
    const int*   src  = (const int*)d_in[1];
    const int*   dst  = (const int*)d_in[2];
    const float* wxW  = (const float*)d_in[3];
    const float* wxb  = (const float*)d_in[4];
    const float* gatW = (const float*)d_in[5];
    const float* gatb = (const float*)d_in[6];
    const float* attl = (const float*)d_in[7];
    const float* attr = (const float*)d_in[8];
    const float* igW  = (const float*)d_in[9];
    const float* igb  = (const float*)d_in[10];
    const float* fgW  = (const float*)d_in[11];
    const float* fgb  = (const float*)d_in[12];
    const float* ogW  = (const float*)d_in[13];
    const float* ogb  = (const float*)d_in[14];
    const float* stW  = (const float*)d_in[15];
    const float* stb  = (const float*)d_in[16];
    const float* outW = (const float*)d_in[17];
    const float* outb = (const float*)d_in[18];

    char* w = (char*)d_ws;
    auto alloc = [&](size_t bytes)->char* { char* p = w; w += (bytes + 255) & ~(size_t)255; return p; };
    const size_t NH = (size_t)NN * HH;
    u16*   muB    = (u16*)alloc(NH*2);            // h0 -> mu (bf16 master)
    u16*   zB     = (u16*)alloc(NH*2);
    u16*   coll0  = (u16*)alloc(NH*2);
    u16*   coll1  = (u16*)alloc(NH*2);
    u16*   coll2  = (u16*)alloc(NH*2);
    float* cbuf   = (float*)alloc(NH*4);
    float* Ibuf   = (float*)alloc(NH*4);
    float* Tbuf   = (float*)alloc(NH*4);
    float* el     = (float*)alloc((size_t)NN*4);
    float* er     = (float*)alloc((size_t)NN*4);
    float* ev     = (float*)alloc((size_t)EE*4);
    int*   deg    = (int*)alloc((size_t)NN*4);
    int*   cursor = (int*)alloc((size_t)NN*4);
    int*   rp     = (int*)alloc((size_t)NN*4);
    int*   bsum   = (int*)alloc(256*4);
    int*   eidx   = (int*)alloc((size_t)EE*4);
    u16*   btpool = (u16*)alloc(483328*2);
    u16* wxT  = btpool;            // [128][256]
    u16* gatT = btpool + 32768;    // 3 x [128][128]
    u16* igT  = btpool + 81920;    // 3 x [128][256]
    u16* fgT  = btpool + 180224;
    u16* ogT  = btpool + 278528;
    u16* stT  = btpool + 376832;
    u16* outT = btpool + 475136;   // [64][128]
    u16* coll[3] = {coll0, coll1, coll2};

    // ---- weight transposes (17 matrices, one batched launch) ----
    WTs ws_h;
    ws_h.t[0] = {wxW, wxT, IN_D, HH};
    for (int i=0;i<3;i++) ws_h.t[1+i]  = {gatW + (size_t)i*HH*HH,    gatT + i*HH*HH,    HH,    HH};
    for (int i=0;i<3;i++) ws_h.t[4+i]  = {igW  + (size_t)i*2*HH*HH,  igT  + i*2*HH*HH,  2*HH,  HH};
    for (int i=0;i<3;i++) ws_h.t[7+i]  = {fgW  + (size_t)i*2*HH*HH,  fgT  + i*2*HH*HH,  2*HH,  HH};
    for (int i=0;i<3;i++) ws_h.t[10+i] = {ogW  + (size_t)i*2*HH*HH,  ogT  + i*2*HH*HH,  2*HH,  HH};
    for (int i=0;i<3;i++) ws_h.t[13+i] = {stW  + (size_t)i*2*HH*HH,  stT  + i*2*HH*HH,  2*HH,  HH};
    ws_h.t[16] = {outW, outT, HH, OUT_D};
    wtrans_k<<<dim3(128,17), 256, 0, stream>>>(ws_h);

    // ---- CSR by dst ----
    hipMemsetAsync(deg, 0, (size_t)NN*4, stream);
    hipMemsetAsync(cursor, 0, (size_t)NN*4, stream);
    count_k<<<(EE+255)/256, 256, 0, stream>>>(dst, deg);
    int nb = (NN+255)/256;
    scan1_k<<<nb, 256, 0, stream>>>(deg, rp, bsum, NN);
    scan2_k<<<1, 256, 0, stream>>>(bsum, nb);
    scan3_k<<<nb, 256, 0, stream>>>(rp, bsum, NN);
    fill_k<<<(EE+255)/256, 256, 0, stream>>>(dst, rp, cursor, eidx);

    const int gN = (NN + 63) / 64;   // 782 blocks

    // ---- h0 = x @ wxW + wxb  -> muB (bf16) ----
    mgemm_k<EPI_BF,4,float><<<gN, 256, 0, stream>>>(
        x, (const float*)nullptr, IN_D, IN_D, wxT, wxb, muB, nullptr, nullptr, nullptr, NN);

    // ---- GAT layers ----
    const u16* hin = muB;
    for (int i = 0; i < DEPTH; ++i) {
        mgemm_k<EPI_BF,4,u16><<<gN, 256, 0, stream>>>(
            hin, (const u16*)nullptr, HH, HH, gatT + i*HH*HH, nullptr,
            zB, nullptr, nullptr, nullptr, NN);
        eler_k<<<NN, 64, 0, stream>>>(zB, attl + i*HH, attr + i*HH, el, er);
        edge_k<<<(EE+255)/256, 256, 0, stream>>>(src, dst, el, er, ev);
        agg_k<<<NN, 64, 0, stream>>>(zB, ev, eidx, rp, deg, src, gatb + i*HH, coll[i]);
        hin = coll[i];
    }

    // ---- depth (LSTM-style gates) ----
    hipMemsetAsync(cbuf, 0, NH*4, stream);
    for (int i = 0; i < DEPTH; ++i) {
        const u16* A1 = coll[i];
        const u16* A2 = muB;
        mgemm_k<EPI_TANH,4,u16><<<gN, 256, 0, stream>>>(
            A1, A2, HH, 2*HH, stT + i*2*HH*HH, stb + i*HH, Tbuf, nullptr, nullptr, nullptr, NN);
        mgemm_k<EPI_SIG,4,u16><<<gN, 256, 0, stream>>>(
            A1, A2, HH, 2*HH, igT + i*2*HH*HH, igb + i*HH, Ibuf, nullptr, nullptr, nullptr, NN);
        mgemm_k<EPI_CUPD,4,u16><<<gN, 256, 0, stream>>>(
            A1, A2, HH, 2*HH, fgT + i*2*HH*HH, fgb + i*HH, nullptr, cbuf, Ibuf, Tbuf, NN);
        mgemm_k<EPI_MUUPD,4,u16><<<gN, 256, 0, stream>>>(
            A1, A2, HH, 2*HH, ogT + i*2*HH*HH, ogb + i*HH, muB, cbuf, nullptr, nullptr, NN);
    }

    // ---- out = relu(mu @ outW + outb) -> f32 ----
    mgemm_k<EPI_RELU,2,u16><<<gN, 256, 0, stream>>>(
        muB, (const u16*)nullptr, HH, HH, outT, outb, (float*)d_out, nullptr, nullptr, nullptr, NN);
}

// Round 4
// 648.998 us; speedup vs baseline: 3.5134x; 1.1408x over previous
//
#include <hip/hip_runtime.h>
#include <math.h>
#include <type_traits>

#define NN 50000
#define EE 800000
#define IN_D 256
#define HH 128
#define OUT_D 64
#define DEPTH 3

typedef unsigned short u16;
typedef __bf16  bf16x8 __attribute__((ext_vector_type(8)));
typedef short   short8 __attribute__((ext_vector_type(8)));
typedef float   f32x4  __attribute__((ext_vector_type(4)));

__device__ __forceinline__ u16 f2b(float f){
    unsigned u = __float_as_uint(f);
    u += 0x7fff + ((u>>16)&1);            // round-to-nearest-even
    return (u16)(u>>16);
}
__device__ __forceinline__ float b2f(u16 h){ return __uint_as_float(((unsigned)h)<<16); }
__device__ __forceinline__ float sigm(float x){ return 1.f/(1.f+expf(-x)); }

// ---------------- plain MFMA GEMM (h0 and out) ----------------
enum { EPI_BF=0, EPI_RELU=1 };

template<int EPI, int MT, typename TA>   // M = MT*32
__global__ __launch_bounds__(256) void mgemm_k(
    const TA* __restrict__ A1, int K,
    const u16* __restrict__ Bt, const float* __restrict__ bias,
    void* __restrict__ Out, int Nrows)
{
    constexpr int M = MT*32;
    __shared__ u16 As[64*40];
    __shared__ u16 Bs[128*40];
    const int tid  = threadIdx.x;
    const int lane = tid & 63;
    const int w    = tid >> 6;
    const int wrow = (w>>1)*32, wcol = (w&1)*(MT*16);
    const int rb   = blockIdx.x*64;
    f32x4 acc[2][MT] = {};
    const int arow = tid>>2, aseg = tid&3;
    const int gr = rb + arow;
    const int ml = lane & 15, kh = (lane>>4)*8;

    for (int k0 = 0; k0 < K; k0 += 32) {
        short8 v = {};
        if (gr < Nrows) {
            if constexpr (std::is_same<TA,float>::value) {
                const float* p = A1 + (size_t)gr*K + k0 + aseg*8;
                float4 x0 = *(const float4*)p;
                float4 x1 = *(const float4*)(p+4);
                v[0]=(short)f2b(x0.x); v[1]=(short)f2b(x0.y); v[2]=(short)f2b(x0.z); v[3]=(short)f2b(x0.w);
                v[4]=(short)f2b(x1.x); v[5]=(short)f2b(x1.y); v[6]=(short)f2b(x1.z); v[7]=(short)f2b(x1.w);
            } else {
                v = *(const short8*)((const u16*)A1 + (size_t)gr*K + k0 + aseg*8);
            }
        }
        *(short8*)&As[arow*40 + aseg*8] = v;
        #pragma unroll
        for (int c = 0; c < (MT+1)/2; ++c) {
            int idx = tid + c*256;
            if (idx < M*4) {
                int n = idx>>2, sg = idx&3;
                *(short8*)&Bs[n*40 + sg*8] = *(const short8*)(Bt + (size_t)n*K + k0 + sg*8);
            }
        }
        __syncthreads();
        bf16x8 a0 = *(const bf16x8*)&As[(wrow      + ml)*40 + kh];
        bf16x8 a1 = *(const bf16x8*)&As[(wrow + 16 + ml)*40 + kh];
        #pragma unroll
        for (int j = 0; j < MT; ++j) {
            bf16x8 bf = *(const bf16x8*)&Bs[(wcol + j*16 + ml)*40 + kh];
            acc[0][j] = __builtin_amdgcn_mfma_f32_16x16x32_bf16(a0, bf, acc[0][j], 0,0,0);
            acc[1][j] = __builtin_amdgcn_mfma_f32_16x16x32_bf16(a1, bf, acc[1][j], 0,0,0);
        }
        __syncthreads();
    }
    const int rq = (lane>>4)*4;
    #pragma unroll
    for (int i = 0; i < 2; ++i)
    #pragma unroll
    for (int r = 0; r < 4; ++r) {
        int row = rb + wrow + i*16 + rq + r;
        if (row >= Nrows) continue;
        #pragma unroll
        for (int j = 0; j < MT; ++j) {
            int gc = wcol + j*16 + ml;
            float vv = acc[i][j][r];
            if (bias) vv += bias[gc];
            size_t o = (size_t)row*M + gc;
            if (EPI==EPI_BF)   ((u16*)Out)[o]   = f2b(vv);
            if (EPI==EPI_RELU) ((float*)Out)[o] = fmaxf(vv, 0.f);
        }
    }
}

// ---------------- z-GEMM with fused el/er epilogue ----------------
__global__ __launch_bounds__(256) void zel_k(
    const u16* __restrict__ A1,
    const u16* __restrict__ Bt, const float* __restrict__ al, const float* __restrict__ ar,
    u16* __restrict__ Out, float* __restrict__ el, float* __restrict__ er, int Nrows)
{
    __shared__ u16 As[64*40];
    __shared__ u16 Bs[128*40];
    __shared__ float elp[64][2], erp[64][2];
    const int tid  = threadIdx.x;
    const int lane = tid & 63;
    const int w    = tid >> 6;
    const int wrow = (w>>1)*32, wcol = (w&1)*64;
    const int rb   = blockIdx.x*64;
    f32x4 acc[2][4] = {};
    const int arow = tid>>2, aseg = tid&3;
    const int gr = rb + arow;
    const int ml = lane & 15, kh = (lane>>4)*8;

    for (int k0 = 0; k0 < HH; k0 += 32) {
        short8 v = {};
        if (gr < Nrows) v = *(const short8*)(A1 + (size_t)gr*HH + k0 + aseg*8);
        *(short8*)&As[arow*40 + aseg*8] = v;
        #pragma unroll
        for (int c = 0; c < 2; ++c) {
            int idx = tid + c*256;
            int n = idx>>2, sg = idx&3;
            *(short8*)&Bs[n*40 + sg*8] = *(const short8*)(Bt + (size_t)n*HH + k0 + sg*8);
        }
        __syncthreads();
        bf16x8 a0 = *(const bf16x8*)&As[(wrow      + ml)*40 + kh];
        bf16x8 a1 = *(const bf16x8*)&As[(wrow + 16 + ml)*40 + kh];
        #pragma unroll
        for (int j = 0; j < 4; ++j) {
            bf16x8 bf = *(const bf16x8*)&Bs[(wcol + j*16 + ml)*40 + kh];
            acc[0][j] = __builtin_amdgcn_mfma_f32_16x16x32_bf16(a0, bf, acc[0][j], 0,0,0);
            acc[1][j] = __builtin_amdgcn_mfma_f32_16x16x32_bf16(a1, bf, acc[1][j], 0,0,0);
        }
        __syncthreads();
    }
    const int rq = (lane>>4)*4;
    // write z (bf16) + accumulate el/er partials
    float pel[2][4] = {}, per2[2][4] = {};
    #pragma unroll
    for (int j = 0; j < 4; ++j) {
        int gc = wcol + j*16 + ml;
        float alc = al[gc], arc = ar[gc];
        #pragma unroll
        for (int i = 0; i < 2; ++i)
        #pragma unroll
        for (int r = 0; r < 4; ++r) {
            int row = rb + wrow + i*16 + rq + r;
            float vv = acc[i][j][r];
            if (row < Nrows) Out[(size_t)row*HH + gc] = f2b(vv);
            pel[i][r]  = fmaf(vv, alc, pel[i][r]);
            per2[i][r] = fmaf(vv, arc, per2[i][r]);
        }
    }
    #pragma unroll
    for (int msk = 1; msk < 16; msk <<= 1)
        #pragma unroll
        for (int i = 0; i < 2; ++i)
        #pragma unroll
        for (int r = 0; r < 4; ++r) {
            pel[i][r]  += __shfl_xor(pel[i][r],  msk);
            per2[i][r] += __shfl_xor(per2[i][r], msk);
        }
    if (ml == 0) {
        #pragma unroll
        for (int i = 0; i < 2; ++i)
        #pragma unroll
        for (int r = 0; r < 4; ++r) {
            int lr = wrow + i*16 + rq + r;
            elp[lr][w&1] = pel[i][r];
            erp[lr][w&1] = per2[i][r];
        }
    }
    __syncthreads();
    if (tid < 64) {
        int row = rb + tid;
        if (row < Nrows) {
            el[row] = elp[tid][0] + elp[tid][1];
            er[row] = erp[tid][0] + erp[tid][1];
        }
    }
}

// ---------------- fused 4-gate GEMM + c/mu update ----------------
// Bt4: [512][256] = [ig(128) | st(128) | fg(128) | og(128)] rows, K=256.
// A = concat(coll, mu).  In-place mu write is safe (block reads/writes only its 64 rows).
template<bool FIRST>
__global__ __launch_bounds__(256) void gates_k(
    const u16* __restrict__ A1, const u16* __restrict__ A2,
    const u16* __restrict__ Bt4,
    const float* __restrict__ igb, const float* __restrict__ stb,
    const float* __restrict__ fgb, const float* __restrict__ ogb,
    float* __restrict__ cbuf, u16* __restrict__ mu, int Nrows)
{
    __shared__ u16 As[64*40];
    __shared__ u16 Bs[512*40];
    const int tid  = threadIdx.x;
    const int lane = tid & 63;
    const int w    = tid >> 6;
    const int wrow = (w>>1)*32, wcol = (w&1)*64;
    const int rb   = blockIdx.x*64;
    f32x4 acc[2][4][4] = {};   // [rowtile][gate][coltile]
    const int arow = tid>>2, aseg = tid&3;
    const int gr = rb + arow;
    const int ml = lane & 15, kh = (lane>>4)*8;

    for (int k0 = 0; k0 < 2*HH; k0 += 32) {
        const u16* Ap = (k0 < HH) ? A1 : A2;
        int kk = (k0 < HH) ? k0 : k0 - HH;
        short8 v = {};
        if (gr < Nrows) v = *(const short8*)(Ap + (size_t)gr*HH + kk + aseg*8);
        *(short8*)&As[arow*40 + aseg*8] = v;
        #pragma unroll
        for (int c = 0; c < 8; ++c) {
            int idx = tid + c*256;
            int n = idx>>2, sg = idx&3;
            *(short8*)&Bs[n*40 + sg*8] = *(const short8*)(Bt4 + (size_t)n*2*HH + k0 + sg*8);
        }
        __syncthreads();
        bf16x8 a0 = *(const bf16x8*)&As[(wrow      + ml)*40 + kh];
        bf16x8 a1 = *(const bf16x8*)&As[(wrow + 16 + ml)*40 + kh];
        #pragma unroll
        for (int g = 0; g < 4; ++g)
        #pragma unroll
        for (int j = 0; j < 4; ++j) {
            bf16x8 bf = *(const bf16x8*)&Bs[(g*128 + wcol + j*16 + ml)*40 + kh];
            acc[0][g][j] = __builtin_amdgcn_mfma_f32_16x16x32_bf16(a0, bf, acc[0][g][j], 0,0,0);
            acc[1][g][j] = __builtin_amdgcn_mfma_f32_16x16x32_bf16(a1, bf, acc[1][g][j], 0,0,0);
        }
        __syncthreads();
    }
    const int rq = (lane>>4)*4;
    #pragma unroll
    for (int i = 0; i < 2; ++i)
    #pragma unroll
    for (int r = 0; r < 4; ++r) {
        int row = rb + wrow + i*16 + rq + r;
        if (row >= Nrows) continue;
        #pragma unroll
        for (int j = 0; j < 4; ++j) {
            int gc = wcol + j*16 + ml;
            size_t o = (size_t)row*HH + gc;
            float ig = sigm (acc[i][0][j][r] + igb[gc]);
            float st = tanhf(acc[i][1][j][r] + stb[gc]);
            float fg = sigm (acc[i][2][j][r] + fgb[gc]);
            float og = sigm (acc[i][3][j][r] + ogb[gc]);
            float P  = ig * st;
            float cn = FIRST ? P : fmaf(fg, cbuf[o], P);
            cbuf[o] = cn;
            mu[o] = f2b(og * tanhf(cn));
        }
    }
}

// ---------------- weight transpose+convert: dst[m*K+k] = src[k*M+m] ----------------
struct WT  { const float* s; u16* d; int K; int M; };
struct WTs { WT t[17]; };
__global__ __launch_bounds__(256) void wtrans_k(WTs ws){
    const WT t = ws.t[blockIdx.y];
    int o = blockIdx.x*256 + threadIdx.x;
    int tot = t.K * t.M;
    if (o >= tot) return;
    int m = o / t.K, k = o - m*t.K;
    t.d[o] = f2b(t.s[(size_t)k*t.M + m]);
}

// ---------------- per-node attention: alpha[p] = softmax over incoming edges ----------------
__global__ __launch_bounds__(256) void attn_k(
    const float* __restrict__ el, const float* __restrict__ er,
    const int* __restrict__ srcs, const int* __restrict__ rp, const int* __restrict__ deg,
    float* __restrict__ alpha)
{
    int n = blockIdx.x*4 + (threadIdx.x>>6);
    if (n >= NN) return;
    int lane = threadIdx.x & 63;
    int start = rp[n], cnt = deg[n];
    float ern = er[n];
    float m = -1e30f;
    for (int i=lane; i<cnt; i+=64) {
        float v = el[srcs[start+i]] + ern;
        v = v >= 0.f ? v : 0.2f*v;
        alpha[start+i] = v;
        m = fmaxf(m, v);
    }
    #pragma unroll
    for (int off=1; off<64; off<<=1) m = fmaxf(m, __shfl_xor(m, off));
    float s = 0.f;
    for (int i=lane; i<cnt; i+=64) s += expf(alpha[start+i] - m);
    #pragma unroll
    for (int off=1; off<64; off<<=1) s += __shfl_xor(s, off);
    float inv = 1.f / fmaxf(s, 1e-16f);
    for (int i=lane; i<cnt; i+=64) alpha[start+i] = expf(alpha[start+i] - m) * inv;
}

// ---------------- per-node weighted gather: h = tanh(sum alpha * z[src] + b) ----------------
__global__ __launch_bounds__(256) void agg_k(
    const u16* __restrict__ z, const float* __restrict__ alpha,
    const int* __restrict__ srcs, const int* __restrict__ rp, const int* __restrict__ deg,
    const float* __restrict__ bias, u16* __restrict__ hout)
{
    int n = blockIdx.x*4 + (threadIdx.x>>6);
    if (n >= NN) return;
    int lane = threadIdx.x & 63;
    int start = rp[n], cnt = deg[n];
    const int slot = lane >> 4;
    const int ch   = (lane & 15) * 8;
    float acc[8] = {};
    for (int i = slot; i < cnt; i += 4) {
        int p = start + i;
        float wgt = alpha[p];
        short8 v = *(const short8*)(z + (size_t)srcs[p]*HH + ch);
        #pragma unroll
        for (int j=0;j<8;j++) acc[j] = fmaf(wgt, b2f((u16)v[j]), acc[j]);
    }
    #pragma unroll
    for (int j=0;j<8;j++){ acc[j] += __shfl_xor(acc[j],16); acc[j] += __shfl_xor(acc[j],32); }
    if (slot == 0) {
        short8 o8;
        #pragma unroll
        for (int j=0;j<8;j++) o8[j] = (short)f2b(tanhf(acc[j] + bias[ch+j]));
        *(short8*)(hout + (size_t)n*HH + ch) = o8;
    }
}

// ---------------- CSR build (by dst) ----------------
__global__ void count_k(const int* __restrict__ dst, int* __restrict__ deg){
    int e = blockIdx.x*256 + threadIdx.x;
    if (e < EE) atomicAdd(&deg[dst[e]], 1);
}
__global__ __launch_bounds__(256) void scan1_k(const int* __restrict__ deg, int* __restrict__ rp,
                                               int* __restrict__ bsum, int n){
    __shared__ int s[256];
    int t = threadIdx.x, idx = blockIdx.x*256 + t;
    int v = (idx < n) ? deg[idx] : 0;
    s[t] = v; __syncthreads();
    for (int off=1; off<256; off<<=1){ int x = (t>=off)? s[t-off] : 0; __syncthreads(); s[t] += x; __syncthreads(); }
    if (idx < n) rp[idx] = s[t] - v;
    if (t == 255) bsum[blockIdx.x] = s[255];
}
__global__ __launch_bounds__(256) void scan2_k(int* __restrict__ bsum, int nb){
    __shared__ int s[256];
    int t = threadIdx.x;
    int v = (t < nb) ? bsum[t] : 0;
    s[t] = v; __syncthreads();
    for (int off=1; off<256; off<<=1){ int x = (t>=off)? s[t-off] : 0; __syncthreads(); s[t] += x; __syncthreads(); }
    if (t < nb) bsum[t] = s[t] - v;
}
__global__ void scan3_k(int* __restrict__ rp, const int* __restrict__ bsum, int n){
    int idx = blockIdx.x*256 + threadIdx.x;
    if (idx < n) rp[idx] += bsum[blockIdx.x];
}
__global__ void fill_k(const int* __restrict__ dst, const int* __restrict__ src,
                       const int* __restrict__ rp, int* __restrict__ cursor,
                       int* __restrict__ srcs){
    int e = blockIdx.x*256 + threadIdx.x;
    if (e >= EE) return;
    int d = dst[e];
    int pos = rp[d] + atomicAdd(&cursor[d], 1);
    srcs[pos] = src[e];
}

extern "C" void kernel_launch(void* const* d_in, const int* in_sizes, int n_in,
                              void* d_out, int out_size, void* d_ws, size_t ws_size,
                              hipStream_t stream)
{
    const float* x    = (const float*)d_in[0];
    const int*   src  = (const int*)d_in[1];
    const int*   dst  = (const int*)d_in[2];
    const float* wxW  = (const float*)d_in[3];
    const float* wxb  = (const float*)d_in[4];
    const float* gatW = (const float*)d_in[5];
    const float* gatb = (const float*)d_in[6];
    const float* attl = (const float*)d_in[7];
    const float* attr = (const float*)d_in[8];
    const float* igW  = (const float*)d_in[9];
    const float* igb  = (const float*)d_in[10];
    const float* fgW  = (const float*)d_in[11];
    const float* fgb  = (const float*)d_in[12];
    const float* ogW  = (const float*)d_in[13];
    const float* ogb  = (const float*)d_in[14];
    const float* stW  = (const float*)d_in[15];
    const float* stb  = (const float*)d_in[16];
    const float* outW = (const float*)d_in[17];
    const float* outb = (const float*)d_in[18];

    char* w = (char*)d_ws;
    auto alloc = [&](size_t bytes)->char* { char* p = w; w += (bytes + 255) & ~(size_t)255; return p; };
    const size_t NH = (size_t)NN * HH;
    u16*   muB    = (u16*)alloc(NH*2);            // h0 -> mu (bf16 master)
    u16*   zB     = (u16*)alloc(NH*2);
    u16*   coll0  = (u16*)alloc(NH*2);
    u16*   coll1  = (u16*)alloc(NH*2);
    u16*   coll2  = (u16*)alloc(NH*2);
    float* cbuf   = (float*)alloc(NH*4);
    float* el     = (float*)alloc((size_t)NN*4);
    float* er     = (float*)alloc((size_t)NN*4);
    float* alpha  = (float*)alloc((size_t)EE*4);
    int*   deg    = (int*)alloc((size_t)NN*4);
    int*   cursor = (int*)alloc((size_t)NN*4);
    int*   rp     = (int*)alloc((size_t)NN*4);
    int*   bsum   = (int*)alloc(256*4);
    int*   srcs   = (int*)alloc((size_t)EE*4);
    u16*   btpool = (u16*)alloc(483328*2);
    u16* wxT   = btpool;            // [128][256]
    u16* gatT  = btpool + 32768;    // 3 x [128][128]
    u16* gate4 = btpool + 81920;    // 3 x [512][256]: [ig|st|fg|og]
    u16* outT  = btpool + 475136;   // [64][128]
    u16* coll[3] = {coll0, coll1, coll2};

    // ---- weight transposes (17 matrices, one batched launch) ----
    WTs ws_h;
    ws_h.t[0] = {wxW, wxT, IN_D, HH};
    for (int i=0;i<3;i++) ws_h.t[1+i]  = {gatW + (size_t)i*HH*HH,   gatT  + i*HH*HH,           HH,   HH};
    for (int i=0;i<3;i++) ws_h.t[4+i]  = {igW  + (size_t)i*2*HH*HH, gate4 + i*131072,          2*HH, HH};
    for (int i=0;i<3;i++) ws_h.t[7+i]  = {stW  + (size_t)i*2*HH*HH, gate4 + i*131072 + 32768,  2*HH, HH};
    for (int i=0;i<3;i++) ws_h.t[10+i] = {fgW  + (size_t)i*2*HH*HH, gate4 + i*131072 + 65536,  2*HH, HH};
    for (int i=0;i<3;i++) ws_h.t[13+i] = {ogW  + (size_t)i*2*HH*HH, gate4 + i*131072 + 98304,  2*HH, HH};
    ws_h.t[16] = {outW, outT, HH, OUT_D};
    wtrans_k<<<dim3(128,17), 256, 0, stream>>>(ws_h);

    // ---- CSR by dst ----
    hipMemsetAsync(deg, 0, (size_t)NN*4, stream);
    hipMemsetAsync(cursor, 0, (size_t)NN*4, stream);
    count_k<<<(EE+255)/256, 256, 0, stream>>>(dst, deg);
    int nb = (NN+255)/256;
    scan1_k<<<nb, 256, 0, stream>>>(deg, rp, bsum, NN);
    scan2_k<<<1, 256, 0, stream>>>(bsum, nb);
    scan3_k<<<nb, 256, 0, stream>>>(rp, bsum, NN);
    fill_k<<<(EE+255)/256, 256, 0, stream>>>(dst, src, rp, cursor, srcs);

    const int gN = (NN + 63) / 64;   // 782 blocks
    const int gA = (NN + 3) / 4;     // 12500 blocks

    // ---- h0 = x @ wxW + wxb  -> muB (bf16) ----
    mgemm_k<EPI_BF,4,float><<<gN, 256, 0, stream>>>(x, IN_D, wxT, wxb, muB, NN);

    // ---- GAT layers ----
    const u16* hin = muB;
    for (int i = 0; i < DEPTH; ++i) {
        zel_k<<<gN, 256, 0, stream>>>(hin, gatT + i*HH*HH, attl + i*HH, attr + i*HH,
                                      zB, el, er, NN);
        attn_k<<<gA, 256, 0, stream>>>(el, er, srcs, rp, deg, alpha);
        agg_k<<<gA, 256, 0, stream>>>(zB, alpha, srcs, rp, deg, gatb + i*HH, coll[i]);
        hin = coll[i];
    }

    // ---- depth (fused 4-gate per layer) ----
    gates_k<true><<<gN, 256, 0, stream>>>(coll[0], muB, gate4,
        igb, stb, fgb, ogb, cbuf, muB, NN);
    for (int i = 1; i < DEPTH; ++i)
        gates_k<false><<<gN, 256, 0, stream>>>(coll[i], muB, gate4 + i*131072,
            igb + i*HH, stb + i*HH, fgb + i*HH, ogb + i*HH, cbuf, muB, NN);

    // ---- out = relu(mu @ outW + outb) -> f32 ----
    mgemm_k<EPI_RELU,2,u16><<<gN, 256, 0, stream>>>(muB, HH, outT, outb, (float*)d_out, NN);
}